// Round 5
// baseline (90.650 us; speedup 1.0000x reference)
//
#include <hip/hip_runtime.h>
#include <stdint.h>

// Chain min-cut / Viterbi, exact fp32 emulation of the reference scan via the
// scalar d-recurrence (d = a0 - a1 of the renormalized carry).
// Round 5: round-3 two-kernel structure (cooperative launch failed in this
// harness) + micro-opts: fabs-based event compare (free input modifier),
// 32-bit mask halves, packed uint4 (e,g) per segment (one 16B store/load),
// occupancy bounds for latency hiding.

#define LAM 0.75f
constexpr int N_TOTAL = 8388608;
constexpr int SEG = 64;
constexpr int NSEG = N_TOTAL / SEG;   // 131072 segments == 64-bit words
constexpr int NBLK = NSEG / 256;      // 512 blocks

// Bit-exact renormalized step: d' = fl(fl(p+e0) - fl(fl(1-p)+e1))
__device__ __forceinline__ float dstep(float d, float p) {
    float e0 = fminf(fmaxf(d, 0.0f), LAM);
    float e1 = fminf(fmaxf(-d, 0.0f), LAM);
    return (p + e0) - ((1.0f - p) + e1);
}

// Exact d at the END of segment 0 (special non-renormalized first step).
__device__ float seg0_end(const float* __restrict__ p) {
    float p0 = p[0];
    float a0 = p0, a1 = 1.0f - p0;
    float t0 = fminf(a0, a1 + LAM);
    float t1 = fminf(a1, a0 + LAM);
    float p1 = p[1];
    float d = (p1 + t0) - ((1.0f - p1) + t1);   // d_1 (renormalized)
    for (int i = 2; i < 64; ++i) d = dstep(d, p[i]);
    return d;
}

union SegU { float4 q[16]; float f[64]; };

// Fused summary+classify: each thread owns one 64-node segment in registers.
// Phase A: monotone hi/lo sandwich summary -> LDS (map forgets its input once
// the clamp saturates; hi==lo bitwise => exact constant map).
// Phase B: entry d from predecessor's constant summary (LDS walk-back; rare
// exact replays; cross-block via redundant recompute), then classify: event
// bit = |d|>lam (fabs = free modifier), sign bit = d>lam, 32-bit halves,
// packed (e_lo,e_hi,g_lo,g_hi) uint4 store.
__global__ __launch_bounds__(256, 3) void k_ab(const float* __restrict__ p,
        uint4* __restrict__ evsg) {
    __shared__ float s_dh[256];
    __shared__ uint8_t s_ok[256];
    const int t = threadIdx.x;
    const int s = blockIdx.x * 256 + t;

    SegU u;
    const float4* g4 = (const float4*)(p + (size_t)s * SEG);
    #pragma unroll
    for (int i = 0; i < 16; ++i) u.q[i] = g4[i];  // 16 independent loads up front

    // ---- Phase A: sandwich summary ----
    float dh = 2.0f, dl = -2.0f;
    #pragma unroll
    for (int i = 0; i < 64; ++i) {
        float pi = u.f[i];
        dh = dstep(dh, pi);
        dl = dstep(dl, pi);
    }
    s_dh[t] = dh;
    s_ok[t] = (dh == dl) ? 1 : 0;
    __syncthreads();

    // ---- Phase B: resolve exact entry d, classify own segment ----
    float d = 0.0f;
    uint32_t e0m = 0, e1m = 0, g0m = 0, g1m = 0;
    if (s == 0) {
        float p0 = u.f[0];
        float a0 = p0, a1 = 1.0f - p0;
        bool f1 = (a1 + LAM) < a0;                // node-0 decisions (non-renorm)
        bool f0 = (a0 + LAM) < a1;
        e0m |= (uint32_t)(f1 || f0); g0m |= (uint32_t)f1;
        float t0 = fminf(a0, a1 + LAM);
        float t1 = fminf(a1, a0 + LAM);
        float p1 = u.f[1];
        d = (p1 + t0) - ((1.0f - p1) + t1);       // d_1
        e0m |= (uint32_t)(fabsf(d) > LAM) << 1;
        g0m |= (uint32_t)(d > LAM) << 1;
        #pragma unroll
        for (int i = 2; i < 32; ++i) {
            d = dstep(d, u.f[i]);
            e0m |= (uint32_t)(fabsf(d) > LAM) << i;
            g0m |= (uint32_t)(d > LAM) << i;
        }
        #pragma unroll
        for (int i = 32; i < 64; ++i) {
            d = dstep(d, u.f[i]);
            e1m |= (uint32_t)(fabsf(d) > LAM) << (i - 32);
            g1m |= (uint32_t)(d > LAM) << (i - 32);
        }
    } else {
        int back = t - 1;
        while (back >= 0 && !s_ok[back]) --back;  // common: stops immediately
        int startSeg;
        if (back >= 0) {
            d = s_dh[back];
            startSeg = blockIdx.x * 256 + back;
        } else {
            // cross-block: recompute predecessor summaries from global (rare >1 iter)
            int v = blockIdx.x * 256 - 1;
            for (;;) {
                if (v == 0) { d = seg0_end(p); startSeg = 0; break; }
                const float4* gv = (const float4*)(p + (size_t)v * SEG);
                float h = 2.0f, l = -2.0f;
                for (int i = 0; i < 16; ++i) {
                    float4 q = gv[i];
                    h = dstep(h, q.x); l = dstep(l, q.x);
                    h = dstep(h, q.y); l = dstep(l, q.y);
                    h = dstep(h, q.z); l = dstep(l, q.z);
                    h = dstep(h, q.w); l = dstep(l, q.w);
                }
                if (h == l) { d = h; startSeg = v; break; }
                --v;
            }
        }
        // exact replay of intermediate non-constant segments (rare; L1/L2-hot)
        for (int v = startSeg + 1; v < s; ++v) {
            const float* sv = p + (size_t)v * SEG;
            for (int i = 0; i < 64; ++i) d = dstep(d, sv[i]);
        }
        #pragma unroll
        for (int i = 0; i < 32; ++i) {
            d = dstep(d, u.f[i]);
            e0m |= (uint32_t)(fabsf(d) > LAM) << i;
            g0m |= (uint32_t)(d > LAM) << i;
        }
        #pragma unroll
        for (int i = 32; i < 64; ++i) {
            d = dstep(d, u.f[i]);
            e1m |= (uint32_t)(fabsf(d) > LAM) << (i - 32);
            g1m |= (uint32_t)(d > LAM) << (i - 32);
        }
    }
    if (s == NSEG - 1) {                          // forced event at N-1: final label
        e1m |= 0x80000000u;
        g1m = (d > 0.0f) ? (g1m | 0x80000000u) : (g1m & 0x7FFFFFFFu);
    }
    evsg[s] = make_uint4(e0m, e1m, g0m, g1m);     // one coalesced 16B store
}

// Fill: label_j = sign of the first event at k >= j. Per block: stage 256
// (ev,sg) words + per-word incoming carry in LDS, then write fully-coalesced
// int4 chunks resolving each label with a ctz on the event suffix mask.
__global__ __launch_bounds__(256, 4) void k_fill(const uint4* __restrict__ evsg,
        int* __restrict__ out) {
    __shared__ uint64_t lev[256];
    __shared__ uint64_t lsg[256];
    __shared__ int lC[256];
    const int t = threadIdx.x;
    const int b = blockIdx.x;
    const int w = b * 256 + t;

    uint4 wv = evsg[w];                           // one coalesced 16B load
    uint64_t e = ((uint64_t)wv.y << 32) | wv.x;
    uint64_t g = ((uint64_t)wv.w << 32) | wv.z;
    lev[t] = e; lsg[t] = g;
    __syncthreads();

    // carry into word w = sign of first event at any position >= 64*(w+1)
    int cur = 0; bool found = false;
    for (int v = t + 1; v < 256; ++v) {           // expected ~1 iteration
        uint64_t evv = lev[v];
        if (evv) { cur = (int)((lsg[v] >> __builtin_ctzll(evv)) & 1ull); found = true; break; }
    }
    if (!found && b + 1 < NBLK) {
        int v = (b + 1) * 256;
        while (v < NSEG) {                         // terminates: word NSEG-1 bit63 forced
            uint4 sv = evsg[v];
            uint64_t evv = ((uint64_t)sv.y << 32) | sv.x;
            if (evv) {
                uint64_t sgv = ((uint64_t)sv.w << 32) | sv.z;
                cur = (int)((sgv >> __builtin_ctzll(evv)) & 1ull);
                break;
            }
            ++v;
        }
    }
    lC[t] = cur;
    __syncthreads();

    int4* o4 = (int4*)out + (size_t)b * 4096;     // block covers 4096 int4 chunks
    #pragma unroll
    for (int i = 0; i < 16; ++i) {
        int c = i * 256 + t;                       // coalesced: consecutive lanes -> consecutive 16B
        int wl = c >> 4;                           // word within block (16 chunks/word)
        int bb = (c & 15) * 4;                     // starting bit of this chunk
        uint64_t we = lev[wl], wg = lsg[wl];       // broadcast reads across 16 lanes
        int wc = lC[wl];
        int4 r;
        uint64_t m = we >> (bb + 0);
        r.x = m ? (int)((wg >> (bb + 0 + __builtin_ctzll(m))) & 1ull) : wc;
        m = we >> (bb + 1);
        r.y = m ? (int)((wg >> (bb + 1 + __builtin_ctzll(m))) & 1ull) : wc;
        m = we >> (bb + 2);
        r.z = m ? (int)((wg >> (bb + 2 + __builtin_ctzll(m))) & 1ull) : wc;
        m = we >> (bb + 3);
        r.w = m ? (int)((wg >> (bb + 3 + __builtin_ctzll(m))) & 1ull) : wc;
        o4[c] = r;
    }
}

extern "C" void kernel_launch(void* const* d_in, const int* in_sizes, int n_in,
                              void* d_out, int out_size, void* d_ws, size_t ws_size,
                              hipStream_t stream) {
    (void)in_sizes; (void)n_in; (void)out_size; (void)ws_size;
    const float* p = (const float*)d_in[0];
    int* out = (int*)d_out;
    uint4* evsg = (uint4*)d_ws;                   // 2 MB

    k_ab<<<dim3(NBLK), dim3(256), 0, stream>>>(p, evsg);
    k_fill<<<dim3(NBLK), dim3(256), 0, stream>>>(evsg, out);
}

// Round 6
// 87.149 us; speedup vs baseline: 1.0402x; 1.0402x over previous
//
#include <hip/hip_runtime.h>
#include <stdint.h>

// Chain min-cut / Viterbi, exact fp32 emulation of the reference scan via the
// scalar d-recurrence (d = a0 - a1 of the renormalized carry).
// Round 6: SEG=32 — double occupancy (4 blocks/CU, 4 waves/SIMD), halve the
// serially-dependent chains (k_ab was latency-bound, not VALU-bound: round-5
// instruction-count micro-opts were neutral). k_fill pairs two 32-bit segment
// words into its 64-bit fill word via one uint4 load.

#define LAM 0.75f
constexpr int N_TOTAL = 8388608;
constexpr int SEG = 32;
constexpr int NSEG = N_TOTAL / SEG;     // 262144 segments (32-bit words)
constexpr int NBLK_AB = NSEG / 256;     // 1024 blocks -> 4 per CU
constexpr int NWORD = N_TOTAL / 64;     // 131072 64-bit fill words
constexpr int NBLK_FILL = NWORD / 256;  // 512 blocks

// Bit-exact renormalized step: d' = fl(fl(p+e0) - fl(fl(1-p)+e1))
__device__ __forceinline__ float dstep(float d, float p) {
    float e0 = fminf(fmaxf(d, 0.0f), LAM);
    float e1 = fminf(fmaxf(-d, 0.0f), LAM);
    return (p + e0) - ((1.0f - p) + e1);
}

// Exact d at the END of segment 0 (special non-renormalized first step).
__device__ float seg0_end(const float* __restrict__ p) {
    float p0 = p[0];
    float a0 = p0, a1 = 1.0f - p0;
    float t0 = fminf(a0, a1 + LAM);
    float t1 = fminf(a1, a0 + LAM);
    float p1 = p[1];
    float d = (p1 + t0) - ((1.0f - p1) + t1);   // d_1 (renormalized)
    for (int i = 2; i < SEG; ++i) d = dstep(d, p[i]);
    return d;
}

union SegU { float4 q[8]; float f[32]; };

// Fused summary+classify: each thread owns one 32-node segment in registers.
// Phase A: monotone hi/lo sandwich summary -> LDS (the step map is a shift
// inside (-lam,lam) and a CONSTANT outside, so once both extreme trajectories
// saturate the same side they coalesce bitwise => exact constant map;
// P(non-coalesce in 32 steps) ~ 1e-4).
// Phase B: entry d from predecessor's constant summary (LDS walk-back; rare
// exact replays; cross-block via redundant recompute), then classify.
__global__ __launch_bounds__(256, 4) void k_ab(const float* __restrict__ p,
        uint2* __restrict__ evsg) {
    __shared__ float s_dh[256];
    __shared__ uint8_t s_ok[256];
    const int t = threadIdx.x;
    const int s = blockIdx.x * 256 + t;

    SegU u;
    const float4* g4 = (const float4*)(p + (size_t)s * SEG);
    #pragma unroll
    for (int i = 0; i < 8; ++i) u.q[i] = g4[i];   // 8 independent loads up front

    // ---- Phase A: sandwich summary (two interleaved independent chains) ----
    float dh = 2.0f, dl = -2.0f;
    #pragma unroll
    for (int i = 0; i < SEG; ++i) {
        float pi = u.f[i];
        dh = dstep(dh, pi);
        dl = dstep(dl, pi);
    }
    s_dh[t] = dh;
    s_ok[t] = (dh == dl) ? 1 : 0;
    __syncthreads();

    // ---- Phase B: resolve exact entry d, classify own segment ----
    float d = 0.0f;
    uint32_t em = 0, gm = 0;
    if (s == 0) {
        float p0 = u.f[0];
        float a0 = p0, a1 = 1.0f - p0;
        bool f1 = (a1 + LAM) < a0;                // node-0 decisions (non-renorm)
        bool f0 = (a0 + LAM) < a1;
        em |= (uint32_t)(f1 || f0); gm |= (uint32_t)f1;
        float t0 = fminf(a0, a1 + LAM);
        float t1 = fminf(a1, a0 + LAM);
        float p1 = u.f[1];
        d = (p1 + t0) - ((1.0f - p1) + t1);       // d_1
        em |= (uint32_t)(fabsf(d) > LAM) << 1;
        gm |= (uint32_t)(d > LAM) << 1;
        #pragma unroll
        for (int i = 2; i < SEG; ++i) {
            d = dstep(d, u.f[i]);
            em |= (uint32_t)(fabsf(d) > LAM) << i;
            gm |= (uint32_t)(d > LAM) << i;
        }
    } else {
        int back = t - 1;
        while (back >= 0 && !s_ok[back]) --back;  // common: stops immediately
        int startSeg;
        if (back >= 0) {
            d = s_dh[back];
            startSeg = blockIdx.x * 256 + back;
        } else {
            // cross-block: recompute predecessor summaries from global (rare >1 iter)
            int v = blockIdx.x * 256 - 1;
            for (;;) {
                if (v == 0) { d = seg0_end(p); startSeg = 0; break; }
                const float4* gv = (const float4*)(p + (size_t)v * SEG);
                float h = 2.0f, l = -2.0f;
                for (int i = 0; i < 8; ++i) {
                    float4 q = gv[i];
                    h = dstep(h, q.x); l = dstep(l, q.x);
                    h = dstep(h, q.y); l = dstep(l, q.y);
                    h = dstep(h, q.z); l = dstep(l, q.z);
                    h = dstep(h, q.w); l = dstep(l, q.w);
                }
                if (h == l) { d = h; startSeg = v; break; }
                --v;
            }
        }
        // exact replay of intermediate non-constant segments (rare; L1/L2-hot)
        for (int v = startSeg + 1; v < s; ++v) {
            const float* sv = p + (size_t)v * SEG;
            for (int i = 0; i < SEG; ++i) d = dstep(d, sv[i]);
        }
        #pragma unroll
        for (int i = 0; i < SEG; ++i) {
            d = dstep(d, u.f[i]);
            em |= (uint32_t)(fabsf(d) > LAM) << i;
            gm |= (uint32_t)(d > LAM) << i;
        }
    }
    if (s == NSEG - 1) {                          // forced event at N-1: final label
        em |= 0x80000000u;
        gm = (d > 0.0f) ? (gm | 0x80000000u) : (gm & 0x7FFFFFFFu);
    }
    evsg[s] = make_uint2(em, gm);                 // one coalesced 8B store
}

// Fill: label_j = sign of the first event at k >= j. Per block: stage 256
// 64-bit (ev,sg) words (built from two adjacent 32-bit segment summaries via
// one uint4 load) + per-word incoming carry in LDS, then write fully-coalesced
// int4 chunks resolving each label with a ctz on the event suffix mask.
__global__ __launch_bounds__(256, 4) void k_fill(const uint4* __restrict__ evsg2,
        int* __restrict__ out) {
    __shared__ uint64_t lev[256];
    __shared__ uint64_t lsg[256];
    __shared__ int lC[256];
    const int t = threadIdx.x;
    const int b = blockIdx.x;
    const int w = b * 256 + t;

    uint4 wv = evsg2[w];                          // (e_lo, g_lo, e_hi, g_hi)
    uint64_t e = ((uint64_t)wv.z << 32) | wv.x;
    uint64_t g = ((uint64_t)wv.w << 32) | wv.y;
    lev[t] = e; lsg[t] = g;
    __syncthreads();

    // carry into word w = sign of first event at any position >= 64*(w+1)
    int cur = 0; bool found = false;
    for (int v = t + 1; v < 256; ++v) {           // expected ~1 iteration
        uint64_t evv = lev[v];
        if (evv) { cur = (int)((lsg[v] >> __builtin_ctzll(evv)) & 1ull); found = true; break; }
    }
    if (!found && b + 1 < NBLK_FILL) {
        int v = (b + 1) * 256;
        while (v < NWORD) {                        // terminates: last word bit63 forced
            uint4 sv = evsg2[v];
            uint64_t evv = ((uint64_t)sv.z << 32) | sv.x;
            if (evv) {
                uint64_t sgv = ((uint64_t)sv.w << 32) | sv.y;
                cur = (int)((sgv >> __builtin_ctzll(evv)) & 1ull);
                break;
            }
            ++v;
        }
    }
    lC[t] = cur;
    __syncthreads();

    int4* o4 = (int4*)out + (size_t)b * 4096;     // block covers 4096 int4 chunks
    #pragma unroll
    for (int i = 0; i < 16; ++i) {
        int c = i * 256 + t;                       // coalesced: consecutive lanes -> consecutive 16B
        int wl = c >> 4;                           // word within block (16 chunks/word)
        int bb = (c & 15) * 4;                     // starting bit of this chunk
        uint64_t we = lev[wl], wg = lsg[wl];       // broadcast reads across 16 lanes
        int wc = lC[wl];
        int4 r;
        uint64_t m = we >> (bb + 0);
        r.x = m ? (int)((wg >> (bb + 0 + __builtin_ctzll(m))) & 1ull) : wc;
        m = we >> (bb + 1);
        r.y = m ? (int)((wg >> (bb + 1 + __builtin_ctzll(m))) & 1ull) : wc;
        m = we >> (bb + 2);
        r.z = m ? (int)((wg >> (bb + 2 + __builtin_ctzll(m))) & 1ull) : wc;
        m = we >> (bb + 3);
        r.w = m ? (int)((wg >> (bb + 3 + __builtin_ctzll(m))) & 1ull) : wc;
        o4[c] = r;
    }
}

extern "C" void kernel_launch(void* const* d_in, const int* in_sizes, int n_in,
                              void* d_out, int out_size, void* d_ws, size_t ws_size,
                              hipStream_t stream) {
    (void)in_sizes; (void)n_in; (void)out_size; (void)ws_size;
    const float* p = (const float*)d_in[0];
    int* out = (int*)d_out;
    uint2* evsg = (uint2*)d_ws;                   // 2 MB

    k_ab<<<dim3(NBLK_AB), dim3(256), 0, stream>>>(p, evsg);
    k_fill<<<dim3(NBLK_FILL), dim3(256), 0, stream>>>((const uint4*)evsg, out);
}